// Round 8
// baseline (9754.577 us; speedup 1.0000x reference)
//
#include <hip/hip_runtime.h>

#define T_DIM 512
#define B_DIM 64
#define H_DIM 1024
#define NQP 288                 // k-quads per gate, padded (256 real + 32 zero)

// ws layout (floats):
//   Wv   [6][NQP][H][4]  masked, k-quad-interleaved, zero-padded quads 256..287
//   hbuf [2][B][H]       hidden ping-pong (device-coherent via agent-scope ops)
//   pmax [T][B][32]      per-pair label maxes
//   barc [8][64]         per-bgroup monotone barrier counters

// ---------------- prep: mask + k-quad interleave + zero pad ----------------
__global__ __launch_bounds__(256) void prep_interleave(
    const float* __restrict__ Wir, const float* __restrict__ Wiz, const float* __restrict__ Win,
    const float* __restrict__ Whr, const float* __restrict__ Whz, const float* __restrict__ Whn,
    float* __restrict__ Wv)
{
    const float* srcs[6] = {Wir, Wiz, Win, Whr, Whz, Whn};
    const int kq = blockIdx.x;                    // 0..287
    const int j  = blockIdx.y * 256 + threadIdx.x;
    const int g  = blockIdx.z;
    const float* src = srcs[g];
    float tmp[4];
    #pragma unroll
    for (int u = 0; u < 4; ++u) {
        const int k = 4 * kq + u;
        float w = 0.0f;
        if (k < H_DIM) {
            w = src[(size_t)k * H_DIM + j];
            if (k < j) w = 0.0f;                  // tril mask
        }
        tmp[u] = w;
    }
    float4* dst = (float4*)Wv + ((size_t)g * NQP + kq) * H_DIM + j;
    *dst = make_float4(tmp[0], tmp[1], tmp[2], tmp[3]);
}

__global__ __launch_bounds__(256) void init_h(const float* __restrict__ h0,
                                              float* __restrict__ hbuf,
                                              unsigned* __restrict__ barc)
{
    if (blockIdx.x < 256) {
        const int i = blockIdx.x * 256 + threadIdx.x;
        if (i < B_DIM * H_DIM) hbuf[i] = h0[i];
    } else {
        #pragma unroll
        for (int k = 0; k < 2; ++k) barc[threadIdx.x + 256 * k] = 0u;
    }
}

// ---------------- main: 256 WGs x 1024 threads (1 WG/CU, 16 waves), coop launch ------
// 64 j-blocks of 16 cols; pair P = blocks (P, 63-P). 32 pairs x 8 bgroups (8 b rows)
// = 256 WGs. Waves 0-7 compute block A, waves 8-15 block B (per-SIMD balanced:
// QPHA+QPHB==9 for all pairs). Lane = (jl 0..15 column, sk 0..3 k-subslot); per block
// 32 slots (8 waves x 4 sk). Per-bgroup 32-WG monotone barrier; agent-scope h exchange.
__global__ __launch_bounds__(1024, 4) void gru_main(
    const float* __restrict__ x,      // [T,B,H]
    const float* __restrict__ Wv,     // [6,NQP,H,4]
    const float* __restrict__ bir, const float* __restrict__ bhr,
    const float* __restrict__ biz, const float* __restrict__ bhz,
    const float* __restrict__ bin_, const float* __restrict__ bhn,
    const float* __restrict__ Wout, const float* __restrict__ bout,
    float* __restrict__ hbuf,         // [2,B,H]
    float* __restrict__ pmax,         // [T,B,32]
    unsigned* __restrict__ barc)      // [8][64]
{
    __shared__ float4 sxh[NQP][17];   // [kq_rel][c] c<8: x rows b0..b0+7, c 8..15: h rows
    __shared__ float4 red[16][8][16]; // [wave][b][jl] sk-folded partials (r,z,ni,nh)
    __shared__ float  mxs[8][2];      // [b][blk] label maxes

    const int tid  = threadIdx.x;
    const int lane = tid & 63;
    const int jl   = lane & 15;       // column within 16-block
    const int sk   = lane >> 4;       // k sub-slot 0..3
    const int ww   = tid >> 6;        // 0..15
    const int blkw = ww >> 3;         // 0: block A, 1: block B
    const int wb   = ww & 7;          // wave-within-block

    const int pair = blockIdx.x & 31;
    const int bg   = blockIdx.x >> 5; // 0..7 barrier group
    const int b0   = bg * 8;

    const int kq0   = 4 * pair;              // staged quad origin
    const int nreal = 256 - kq0;             // real staged rel-quads

    const int Q0A  = 4 * pair;
    const int QPHA = (256 - 4 * pair + 31) >> 5;   // 5..8
    const int Q0B  = 4 * (63 - pair);
    const int QPHB = (4 * pair + 4 + 31) >> 5;     // 1..4  (QPHA+QPHB == 9 for all pairs)

    // this thread's compute assignment (fixed for the whole kernel)
    const int j0  = blkw ? 16 * (63 - pair) : 16 * pair;
    const int Q0  = blkw ? Q0B : Q0A;
    const int QPH = blkw ? QPHB : QPHA;
    const int slot = (wb << 2) | sk;          // 0..31
    const int qs  = Q0 + slot * QPH;
    const int j   = j0 + jl;

    // epilogue per-thread constants (tid<256: blk = tid>>7, b = (tid>>4)&7, jl = tid&15)
    const int ejl = tid & 15;
    const int ej  = ((tid >> 7) ? 16 * (63 - pair) : 16 * pair) + ejl;
    float c_bir = 0, c_bhr = 0, c_biz = 0, c_bhz = 0, c_bin = 0, c_bhn = 0, c_wo = 0, bo = 0;
    if (tid < 256) {
        c_bir = bir[ej]; c_bhr = bhr[ej]; c_biz = biz[ej]; c_bhz = bhz[ej];
        c_bin = bin_[ej]; c_bhn = bhn[ej]; c_wo = Wout[ej]; bo = bout[0];
    }

    const float4* Wv4 = (const float4*)Wv;
    const float4* g0 = Wv4 + (size_t)0 * NQP * H_DIM + j;
    const float4* g1 = Wv4 + (size_t)1 * NQP * H_DIM + j;
    const float4* g2 = Wv4 + (size_t)2 * NQP * H_DIM + j;
    const float4* g3 = Wv4 + (size_t)3 * NQP * H_DIM + j;
    const float4* g4 = Wv4 + (size_t)4 * NQP * H_DIM + j;
    const float4* g5 = Wv4 + (size_t)5 * NQP * H_DIM + j;

    unsigned* mybar = barc + bg * 64;

    // zero sxh once: pad rows (>= nreal) must stay zero (padded weight quads hit them)
    for (int i = tid; i < NQP * 17; i += 1024)
        ((float4*)sxh)[i] = make_float4(0.f, 0.f, 0.f, 0.f);
    __syncthreads();

    for (int t = 0; t < T_DIM; ++t) {
        const float* hid  = hbuf + (size_t)(t & 1) * (B_DIM * H_DIM);
        float*       hidn = hbuf + (size_t)((t + 1) & 1) * (B_DIM * H_DIM);
        const float* xt   = x + (size_t)t * (B_DIM * H_DIM);

        // ---- stage x,h (8 rows each) into quad-major layout; one channel per wave ----
        {
            const int c = ww;                             // 0..15
            const int b = b0 + (c & 7);
            if (c < 8) {
                const float* src = xt + (size_t)b * H_DIM;
                #pragma unroll
                for (int it = 0; it < 4; ++it) {
                    const int r = (tid & 63) + (it << 6);
                    if (r < nreal)
                        sxh[r][c] = *(const float4*)(src + 4 * (kq0 + r));
                }
            } else {
                float* src = (float*)hid + (size_t)b * H_DIM;
                #pragma unroll
                for (int it = 0; it < 4; ++it) {
                    const int r = (tid & 63) + (it << 6);
                    if (r < nreal) {
                        float* s4 = src + 4 * (kq0 + r);
                        float4 v;   // agent-scope loads: read h at the coherence point
                        v.x = __hip_atomic_load(s4 + 0, __ATOMIC_RELAXED, __HIP_MEMORY_SCOPE_AGENT);
                        v.y = __hip_atomic_load(s4 + 1, __ATOMIC_RELAXED, __HIP_MEMORY_SCOPE_AGENT);
                        v.z = __hip_atomic_load(s4 + 2, __ATOMIC_RELAXED, __HIP_MEMORY_SCOPE_AGENT);
                        v.w = __hip_atomic_load(s4 + 3, __ATOMIC_RELAXED, __HIP_MEMORY_SCOPE_AGENT);
                        sxh[r][c] = v;
                    }
                }
            }
        }
        __syncthreads();

        // ---- compute: this wave's block, 8 b-rows, QPH quads, prefetch depth 1 ----
        float4 acc[8];
        #pragma unroll
        for (int i = 0; i < 8; ++i) acc[i] = make_float4(0.f, 0.f, 0.f, 0.f);

        {
            int qi  = qs * H_DIM;                         // 32-bit float4 index
            int row = qs - kq0;
            float4 cw0 = g0[qi], cw1 = g1[qi], cw2 = g2[qi],
                   cw3 = g3[qi], cw4 = g4[qi], cw5 = g5[qi];

            for (int iq = 0; iq < QPH; ++iq) {
                const int qn = qi + H_DIM;                // prefetch next (pad-safe)
                const float4 nw0 = g0[qn], nw1 = g1[qn], nw2 = g2[qn],
                             nw3 = g3[qn], nw4 = g4[qn], nw5 = g5[qn];
                #pragma unroll
                for (int b = 0; b < 8; ++b) {
                    const float4 xv = sxh[row][b];
                    const float4 hv = sxh[row][8 + b];
#define ACC(c) \
                    acc[b].x = fmaf(xv.c, cw0.c, fmaf(hv.c, cw3.c, acc[b].x)); \
                    acc[b].y = fmaf(xv.c, cw1.c, fmaf(hv.c, cw4.c, acc[b].y)); \
                    acc[b].z = fmaf(xv.c, cw2.c, acc[b].z); \
                    acc[b].w = fmaf(hv.c, cw5.c, acc[b].w);
                    ACC(x) ACC(y) ACC(z) ACC(w)
#undef ACC
                }
                cw0 = nw0; cw1 = nw1; cw2 = nw2; cw3 = nw3; cw4 = nw4; cw5 = nw5;
                qi = qn; row += 1;
            }
        }

        // fold the 4 sk sub-slots in-register (xor16 + xor32 span the sk bits)
        #pragma unroll
        for (int b = 0; b < 8; ++b) {
            acc[b].x += __shfl_xor(acc[b].x, 16); acc[b].y += __shfl_xor(acc[b].y, 16);
            acc[b].z += __shfl_xor(acc[b].z, 16); acc[b].w += __shfl_xor(acc[b].w, 16);
            acc[b].x += __shfl_xor(acc[b].x, 32); acc[b].y += __shfl_xor(acc[b].y, 32);
            acc[b].z += __shfl_xor(acc[b].z, 32); acc[b].w += __shfl_xor(acc[b].w, 32);
        }
        if (lane < 16) {
            #pragma unroll
            for (int b = 0; b < 8; ++b) red[ww][b][jl] = acc[b];
        }
        __syncthreads();

        // ---- epilogue: 256 threads = (blk 2) x (b 8) x (jl 16) ----
        if (tid < 256) {
            const int blk = tid >> 7;
            const int b   = (tid >> 4) & 7;
            const int wbase = blk * 8;
            float4 s = red[wbase][b][ejl];
            #pragma unroll
            for (int w2 = 1; w2 < 8; ++w2) {
                const float4 v = red[wbase + w2][b][ejl];
                s.x += v.x; s.y += v.y; s.z += v.z; s.w += v.w;
            }
            const int rr = (ej >> 2) - kq0;
            const float4 xq = sxh[rr][b];
            const float4 hq = sxh[rr][8 + b];
            const float xv = ((const float*)&xq)[ej & 3];
            const float hv = ((const float*)&hq)[ej & 3];
            const float rp = s.x + c_bir * xv + c_bhr;
            const float zp = s.y + c_biz * xv + c_bhz;
            const float r  = 1.0f / (1.0f + expf(-rp));
            const float z  = 1.0f / (1.0f + expf(-zp));
            const float np = s.z + c_bin * xv + r * (s.w + c_bhn);
            const float n  = tanhf(np);
            const float hnew = hv * z + (1.0f - z) * n;
            __hip_atomic_store(&hidn[(size_t)(b0 + b) * H_DIM + ej], hnew,
                               __ATOMIC_RELAXED, __HIP_MEMORY_SCOPE_AGENT);
            float lab = (1.0f / (1.0f + expf(-(hnew * c_wo + bo)))) * xv;
            #pragma unroll
            for (int off = 8; off; off >>= 1)
                lab = fmaxf(lab, __shfl_xor(lab, off));
            if (ejl == 0) mxs[b][blk] = lab;
        }
        __syncthreads();

        if (tid < 8)
            pmax[((size_t)t * B_DIM + b0 + tid) * 32 + pair] = fmaxf(mxs[tid][0], mxs[tid][1]);

        // ---- per-bgroup 32-WG monotone barrier (release RMW, relaxed spin) ----
        if (tid == 0) {
            __hip_atomic_fetch_add(mybar, 1u, __ATOMIC_RELEASE, __HIP_MEMORY_SCOPE_AGENT);
            const unsigned tgt = 32u * (unsigned)(t + 1);
            while (__hip_atomic_load(mybar, __ATOMIC_RELAXED, __HIP_MEMORY_SCOPE_AGENT) < tgt)
                __builtin_amdgcn_s_sleep(2);
        }
        __syncthreads();
    }
}

// ---------------- finalize ----------------
__global__ __launch_bounds__(256) void finalize(const float* __restrict__ pmax, int* __restrict__ out)
{
    const int i = blockIdx.x * 256 + threadIdx.x; // 0..T*B-1
    if (i >= T_DIM * B_DIM) return;
    const float4* pm = (const float4*)(pmax + (size_t)i * 32);
    float m = -3.4e38f;
    #pragma unroll
    for (int q = 0; q < 8; ++q) {
        const float4 v = pm[q];
        m = fmaxf(m, fmaxf(fmaxf(v.x, v.y), fmaxf(v.z, v.w)));
    }
    out[i] = (m >= 0.5f) ? 1 : -1;
}

extern "C" void kernel_launch(void* const* d_in, const int* in_sizes, int n_in,
                              void* d_out, int out_size, void* d_ws, size_t ws_size,
                              hipStream_t stream)
{
    const float* x    = (const float*)d_in[0];
    const float* h0   = (const float*)d_in[1];
    const float* W_ir = (const float*)d_in[2];
    const float* W_hr = (const float*)d_in[3];
    const float* W_iz = (const float*)d_in[4];
    const float* W_hz = (const float*)d_in[5];
    const float* W_in = (const float*)d_in[6];
    const float* W_hn = (const float*)d_in[7];
    const float* b_ir = (const float*)d_in[8];
    const float* b_hr = (const float*)d_in[9];
    const float* b_iz = (const float*)d_in[10];
    const float* b_hz = (const float*)d_in[11];
    const float* b_in = (const float*)d_in[12];
    const float* b_hn = (const float*)d_in[13];
    const float* W_out = (const float*)d_in[14];
    const float* b_out = (const float*)d_in[15];

    float* ws   = (float*)d_ws;
    float* Wv   = ws;                                        // 6*NQP*H*4 floats (~28.3 MB)
    float* hbuf = Wv + (size_t)6 * NQP * H_DIM * 4;          // 2*B*H
    float* pmax = hbuf + (size_t)2 * B_DIM * H_DIM;          // T*B*32 (4 MB)
    unsigned* barc = (unsigned*)(pmax + (size_t)T_DIM * B_DIM * 32); // 8*64 uints

    prep_interleave<<<dim3(NQP, 4, 6), 256, 0, stream>>>(W_ir, W_iz, W_in, W_hr, W_hz, W_hn, Wv);
    init_h<<<dim3(257), 256, 0, stream>>>(h0, hbuf, barc);

    void* args[] = {(void*)&x, (void*)&Wv,
                    (void*)&b_ir, (void*)&b_hr, (void*)&b_iz, (void*)&b_hz,
                    (void*)&b_in, (void*)&b_hn, (void*)&W_out, (void*)&b_out,
                    (void*)&hbuf, (void*)&pmax, (void*)&barc};
    hipLaunchCooperativeKernel((const void*)gru_main, dim3(256), dim3(1024), args, 0, stream);

    finalize<<<dim3(T_DIM * B_DIM / 256), 256, 0, stream>>>(pmax, (int*)d_out);
}

// Round 10
// 9446.018 us; speedup vs baseline: 1.0327x; 1.0327x over previous
//
#include <hip/hip_runtime.h>

#define T_DIM 512
#define B_DIM 64
#define H_DIM 1024
#define NQP 288                 // k-quads per gate, padded (256 real + 32 zero)

// ws layout:
//   Wv   [6][NQP][H][4] bf16 (ushort)  masked, k-quad-interleaved, zero-padded
//   hbuf [2][B][H] f32                 hidden ping-pong (agent-scope coherent)
//   pmax [T][B][32] f32                per-pair label maxes
//   barc [8][64] u32                   per-bgroup monotone barrier counters

__device__ __forceinline__ unsigned short f2bf(float f) {
    unsigned u = __float_as_uint(f);
    unsigned r = (u + 0x7FFFu + ((u >> 16) & 1u)) >> 16;   // RNE
    return (unsigned short)r;
}

// bf16x4 -> float4 (shift<<16); function, not macro (macro param captured member .w)
__device__ __forceinline__ float4 bf4_to_f4(ushort4 v) {
    return make_float4(__uint_as_float((unsigned)v.x << 16),
                       __uint_as_float((unsigned)v.y << 16),
                       __uint_as_float((unsigned)v.z << 16),
                       __uint_as_float((unsigned)v.w << 16));
}

// ---------------- prep: mask + k-quad interleave + bf16 + zero pad ----------------
__global__ __launch_bounds__(256) void prep_interleave(
    const float* __restrict__ Wir, const float* __restrict__ Wiz, const float* __restrict__ Win,
    const float* __restrict__ Whr, const float* __restrict__ Whz, const float* __restrict__ Whn,
    unsigned short* __restrict__ Wv)
{
    const float* srcs[6] = {Wir, Wiz, Win, Whr, Whz, Whn};
    const int kq = blockIdx.x;                    // 0..287
    const int j  = blockIdx.y * 256 + threadIdx.x;
    const int g  = blockIdx.z;
    const float* src = srcs[g];
    ushort4 o;
    unsigned short* po = (unsigned short*)&o;
    #pragma unroll
    for (int u = 0; u < 4; ++u) {
        const int k = 4 * kq + u;
        float w = 0.0f;
        if (k < H_DIM) {
            w = src[(size_t)k * H_DIM + j];
            if (k < j) w = 0.0f;                  // tril mask
        }
        po[u] = f2bf(w);
    }
    ushort4* dst = (ushort4*)Wv + ((size_t)g * NQP + kq) * H_DIM + j;
    *dst = o;
}

__global__ __launch_bounds__(256) void init_h(const float* __restrict__ h0,
                                              float* __restrict__ hbuf,
                                              unsigned* __restrict__ barc)
{
    if (blockIdx.x < 256) {
        const int i = blockIdx.x * 256 + threadIdx.x;
        if (i < B_DIM * H_DIM) hbuf[i] = h0[i];
    } else {
        #pragma unroll
        for (int k = 0; k < 2; ++k) barc[threadIdx.x + 256 * k] = 0u;
    }
}

// ---------------- main: 256 WGs x 1024 threads (1 WG/CU, 16 waves), coop launch ------
// Identical structure to round 8; single change: weights are bf16 (half the stream).
__global__ __launch_bounds__(1024, 4) void gru_main(
    const float* __restrict__ x,      // [T,B,H]
    const unsigned short* __restrict__ Wv, // [6,NQP,H,4] bf16
    const float* __restrict__ bir, const float* __restrict__ bhr,
    const float* __restrict__ biz, const float* __restrict__ bhz,
    const float* __restrict__ bin_, const float* __restrict__ bhn,
    const float* __restrict__ Wout, const float* __restrict__ bout,
    float* __restrict__ hbuf,         // [2,B,H]
    float* __restrict__ pmax,         // [T,B,32]
    unsigned* __restrict__ barc)      // [8][64]
{
    __shared__ float4 sxh[NQP][17];   // [kq_rel][c] c<8: x rows b0..b0+7, c 8..15: h rows
    __shared__ float4 red[16][8][16]; // [wave][b][jl] sk-folded partials (r,z,ni,nh)
    __shared__ float  mxs[8][2];      // [b][blk] label maxes

    const int tid  = threadIdx.x;
    const int lane = tid & 63;
    const int jl   = lane & 15;       // column within 16-block
    const int sk   = lane >> 4;       // k sub-slot 0..3
    const int ww   = tid >> 6;        // 0..15
    const int blkw = ww >> 3;         // 0: block A, 1: block B
    const int wb   = ww & 7;          // wave-within-block

    const int pair = blockIdx.x & 31;
    const int bg   = blockIdx.x >> 5; // 0..7 barrier group
    const int b0   = bg * 8;

    const int kq0   = 4 * pair;              // staged quad origin
    const int nreal = 256 - kq0;             // real staged rel-quads

    const int Q0A  = 4 * pair;
    const int QPHA = (256 - 4 * pair + 31) >> 5;   // 5..8
    const int Q0B  = 4 * (63 - pair);
    const int QPHB = (4 * pair + 4 + 31) >> 5;     // 1..4  (QPHA+QPHB == 9 for all pairs)

    // this thread's compute assignment
    const int j0  = blkw ? 16 * (63 - pair) : 16 * pair;
    const int Q0  = blkw ? Q0B : Q0A;
    const int QPH = blkw ? QPHB : QPHA;
    const int slot = (wb << 2) | sk;          // 0..31
    const int qs  = Q0 + slot * QPH;
    const int j   = j0 + jl;

    // epilogue per-thread constants (tid<256: blk = tid>>7, b = (tid>>4)&7, jl = tid&15)
    const int ejl = tid & 15;
    const int ej  = ((tid >> 7) ? 16 * (63 - pair) : 16 * pair) + ejl;
    float c_bir = 0, c_bhr = 0, c_biz = 0, c_bhz = 0, c_bin = 0, c_bhn = 0, c_wo = 0, bo = 0;
    if (tid < 256) {
        c_bir = bir[ej]; c_bhr = bhr[ej]; c_biz = biz[ej]; c_bhz = bhz[ej];
        c_bin = bin_[ej]; c_bhn = bhn[ej]; c_wo = Wout[ej]; bo = bout[0];
    }

    const ushort4* Wv4 = (const ushort4*)Wv;
    const ushort4* g0 = Wv4 + (size_t)0 * NQP * H_DIM + j;
    const ushort4* g1 = Wv4 + (size_t)1 * NQP * H_DIM + j;
    const ushort4* g2 = Wv4 + (size_t)2 * NQP * H_DIM + j;
    const ushort4* g3 = Wv4 + (size_t)3 * NQP * H_DIM + j;
    const ushort4* g4 = Wv4 + (size_t)4 * NQP * H_DIM + j;
    const ushort4* g5 = Wv4 + (size_t)5 * NQP * H_DIM + j;

    unsigned* mybar = barc + bg * 64;

    // zero sxh once: pad rows (>= nreal) must stay zero (padded weight quads hit them)
    for (int i = tid; i < NQP * 17; i += 1024)
        ((float4*)sxh)[i] = make_float4(0.f, 0.f, 0.f, 0.f);
    __syncthreads();

    for (int t = 0; t < T_DIM; ++t) {
        const float* hid  = hbuf + (size_t)(t & 1) * (B_DIM * H_DIM);
        float*       hidn = hbuf + (size_t)((t + 1) & 1) * (B_DIM * H_DIM);
        const float* xt   = x + (size_t)t * (B_DIM * H_DIM);

        // ---- stage x,h (8 rows each) into quad-major layout; one channel per wave ----
        {
            const int c = ww;                             // 0..15
            const int b = b0 + (c & 7);
            if (c < 8) {
                const float* src = xt + (size_t)b * H_DIM;
                #pragma unroll
                for (int it = 0; it < 4; ++it) {
                    const int r = (tid & 63) + (it << 6);
                    if (r < nreal)
                        sxh[r][c] = *(const float4*)(src + 4 * (kq0 + r));
                }
            } else {
                float* src = (float*)hid + (size_t)b * H_DIM;
                #pragma unroll
                for (int it = 0; it < 4; ++it) {
                    const int r = (tid & 63) + (it << 6);
                    if (r < nreal) {
                        float* s4 = src + 4 * (kq0 + r);
                        float4 v;   // agent-scope loads: read h at the coherence point
                        v.x = __hip_atomic_load(s4 + 0, __ATOMIC_RELAXED, __HIP_MEMORY_SCOPE_AGENT);
                        v.y = __hip_atomic_load(s4 + 1, __ATOMIC_RELAXED, __HIP_MEMORY_SCOPE_AGENT);
                        v.z = __hip_atomic_load(s4 + 2, __ATOMIC_RELAXED, __HIP_MEMORY_SCOPE_AGENT);
                        v.w = __hip_atomic_load(s4 + 3, __ATOMIC_RELAXED, __HIP_MEMORY_SCOPE_AGENT);
                        sxh[r][c] = v;
                    }
                }
            }
        }
        __syncthreads();

        // ---- compute: this wave's block, 8 b-rows, QPH quads, prefetch depth 1 ----
        float4 acc[8];
        #pragma unroll
        for (int i = 0; i < 8; ++i) acc[i] = make_float4(0.f, 0.f, 0.f, 0.f);

        {
            int qi  = qs * H_DIM;                         // 32-bit ushort4 index
            int row = qs - kq0;
            ushort4 cw0 = g0[qi], cw1 = g1[qi], cw2 = g2[qi],
                    cw3 = g3[qi], cw4 = g4[qi], cw5 = g5[qi];

            for (int iq = 0; iq < QPH; ++iq) {
                const int qn = qi + H_DIM;                // prefetch next (pad-safe)
                const ushort4 nw0 = g0[qn], nw1 = g1[qn], nw2 = g2[qn],
                              nw3 = g3[qn], nw4 = g4[qn], nw5 = g5[qn];
                const float4 fw0 = bf4_to_f4(cw0), fw1 = bf4_to_f4(cw1), fw2 = bf4_to_f4(cw2),
                             fw3 = bf4_to_f4(cw3), fw4 = bf4_to_f4(cw4), fw5 = bf4_to_f4(cw5);
                #pragma unroll
                for (int b = 0; b < 8; ++b) {
                    const float4 xv = sxh[row][b];
                    const float4 hv = sxh[row][8 + b];
#define ACC(c) \
                    acc[b].x = fmaf(xv.c, fw0.c, fmaf(hv.c, fw3.c, acc[b].x)); \
                    acc[b].y = fmaf(xv.c, fw1.c, fmaf(hv.c, fw4.c, acc[b].y)); \
                    acc[b].z = fmaf(xv.c, fw2.c, acc[b].z); \
                    acc[b].w = fmaf(hv.c, fw5.c, acc[b].w);
                    ACC(x) ACC(y) ACC(z) ACC(w)
#undef ACC
                }
                cw0 = nw0; cw1 = nw1; cw2 = nw2; cw3 = nw3; cw4 = nw4; cw5 = nw5;
                qi = qn; row += 1;
            }
        }

        // fold the 4 sk sub-slots in-register (xor16 + xor32 span the sk bits)
        #pragma unroll
        for (int b = 0; b < 8; ++b) {
            acc[b].x += __shfl_xor(acc[b].x, 16); acc[b].y += __shfl_xor(acc[b].y, 16);
            acc[b].z += __shfl_xor(acc[b].z, 16); acc[b].w += __shfl_xor(acc[b].w, 16);
            acc[b].x += __shfl_xor(acc[b].x, 32); acc[b].y += __shfl_xor(acc[b].y, 32);
            acc[b].z += __shfl_xor(acc[b].z, 32); acc[b].w += __shfl_xor(acc[b].w, 32);
        }
        if (lane < 16) {
            #pragma unroll
            for (int b = 0; b < 8; ++b) red[ww][b][jl] = acc[b];
        }
        __syncthreads();

        // ---- epilogue: 256 threads = (blk 2) x (b 8) x (jl 16) ----
        if (tid < 256) {
            const int blk = tid >> 7;
            const int b   = (tid >> 4) & 7;
            const int wbase = blk * 8;
            float4 s = red[wbase][b][ejl];
            #pragma unroll
            for (int w2 = 1; w2 < 8; ++w2) {
                const float4 v = red[wbase + w2][b][ejl];
                s.x += v.x; s.y += v.y; s.z += v.z; s.w += v.w;
            }
            const int rr = (ej >> 2) - kq0;
            const float4 xq = sxh[rr][b];
            const float4 hq = sxh[rr][8 + b];
            const float xv = ((const float*)&xq)[ej & 3];
            const float hv = ((const float*)&hq)[ej & 3];
            const float rp = s.x + c_bir * xv + c_bhr;
            const float zp = s.y + c_biz * xv + c_bhz;
            const float r  = 1.0f / (1.0f + expf(-rp));
            const float z  = 1.0f / (1.0f + expf(-zp));
            const float np = s.z + c_bin * xv + r * (s.w + c_bhn);
            const float n  = tanhf(np);
            const float hnew = hv * z + (1.0f - z) * n;
            __hip_atomic_store(&hidn[(size_t)(b0 + b) * H_DIM + ej], hnew,
                               __ATOMIC_RELAXED, __HIP_MEMORY_SCOPE_AGENT);
            float lab = (1.0f / (1.0f + expf(-(hnew * c_wo + bo)))) * xv;
            #pragma unroll
            for (int off = 8; off; off >>= 1)
                lab = fmaxf(lab, __shfl_xor(lab, off));
            if (ejl == 0) mxs[b][blk] = lab;
        }
        __syncthreads();

        if (tid < 8)
            pmax[((size_t)t * B_DIM + b0 + tid) * 32 + pair] = fmaxf(mxs[tid][0], mxs[tid][1]);

        // ---- per-bgroup 32-WG monotone barrier (release RMW, relaxed spin) ----
        if (tid == 0) {
            __hip_atomic_fetch_add(mybar, 1u, __ATOMIC_RELEASE, __HIP_MEMORY_SCOPE_AGENT);
            const unsigned tgt = 32u * (unsigned)(t + 1);
            while (__hip_atomic_load(mybar, __ATOMIC_RELAXED, __HIP_MEMORY_SCOPE_AGENT) < tgt)
                __builtin_amdgcn_s_sleep(2);
        }
        __syncthreads();
    }
}

// ---------------- finalize ----------------
__global__ __launch_bounds__(256) void finalize(const float* __restrict__ pmax, int* __restrict__ out)
{
    const int i = blockIdx.x * 256 + threadIdx.x; // 0..T*B-1
    if (i >= T_DIM * B_DIM) return;
    const float4* pm = (const float4*)(pmax + (size_t)i * 32);
    float m = -3.4e38f;
    #pragma unroll
    for (int q = 0; q < 8; ++q) {
        const float4 v = pm[q];
        m = fmaxf(m, fmaxf(fmaxf(v.x, v.y), fmaxf(v.z, v.w)));
    }
    out[i] = (m >= 0.5f) ? 1 : -1;
}

extern "C" void kernel_launch(void* const* d_in, const int* in_sizes, int n_in,
                              void* d_out, int out_size, void* d_ws, size_t ws_size,
                              hipStream_t stream)
{
    const float* x    = (const float*)d_in[0];
    const float* h0   = (const float*)d_in[1];
    const float* W_ir = (const float*)d_in[2];
    const float* W_hr = (const float*)d_in[3];
    const float* W_iz = (const float*)d_in[4];
    const float* W_hz = (const float*)d_in[5];
    const float* W_in = (const float*)d_in[6];
    const float* W_hn = (const float*)d_in[7];
    const float* b_ir = (const float*)d_in[8];
    const float* b_hr = (const float*)d_in[9];
    const float* b_iz = (const float*)d_in[10];
    const float* b_hz = (const float*)d_in[11];
    const float* b_in = (const float*)d_in[12];
    const float* b_hn = (const float*)d_in[13];
    const float* W_out = (const float*)d_in[14];
    const float* b_out = (const float*)d_in[15];

    unsigned short* Wv = (unsigned short*)d_ws;              // 6*NQP*H*4 bf16 (~14.2 MB)
    float* hbuf = (float*)(Wv + (size_t)6 * NQP * H_DIM * 4);// 2*B*H f32
    float* pmax = hbuf + (size_t)2 * B_DIM * H_DIM;          // T*B*32 f32 (4 MB)
    unsigned* barc = (unsigned*)(pmax + (size_t)T_DIM * B_DIM * 32); // 8*64 u32

    prep_interleave<<<dim3(NQP, 4, 6), 256, 0, stream>>>(W_ir, W_iz, W_in, W_hr, W_hz, W_hn, Wv);
    init_h<<<dim3(257), 256, 0, stream>>>(h0, hbuf, barc);

    void* args[] = {(void*)&x, (void*)&Wv,
                    (void*)&b_ir, (void*)&b_hr, (void*)&b_iz, (void*)&b_hz,
                    (void*)&b_in, (void*)&b_hn, (void*)&W_out, (void*)&b_out,
                    (void*)&hbuf, (void*)&pmax, (void*)&barc};
    hipError_t rc = hipLaunchCooperativeKernel((const void*)gru_main, dim3(256), dim3(1024), args, 0, stream);
    (void)rc;

    finalize<<<dim3(T_DIM * B_DIM / 256), 256, 0, stream>>>(pmax, (int*)d_out);
}

// Round 11
// 9028.754 us; speedup vs baseline: 1.0804x; 1.0462x over previous
//
#include <hip/hip_runtime.h>

#define T_DIM 512
#define B_DIM 64
#define H_DIM 1024
#define NQP 288                 // k-quads per gate, padded (256 real + 32 zero)

// ws layout:
//   Wv   [6][NQP][H][4] bf16 (ushort)  masked, k-quad-interleaved, zero-padded
//   hbuf [2][B][H] f32                 hidden ping-pong (agent-scope coherent)
//   pmax [T][B][32] f32                per-pair label maxes
//   barc [8][64] u32                   per-bgroup monotone barrier counters

__device__ __forceinline__ unsigned short f2bf(float f) {
    unsigned u = __float_as_uint(f);
    unsigned r = (u + 0x7FFFu + ((u >> 16) & 1u)) >> 16;   // RNE
    return (unsigned short)r;
}

// bf16x4 -> float4 (shift<<16)
__device__ __forceinline__ float4 bf4_to_f4(ushort4 v) {
    return make_float4(__uint_as_float((unsigned)v.x << 16),
                       __uint_as_float((unsigned)v.y << 16),
                       __uint_as_float((unsigned)v.z << 16),
                       __uint_as_float((unsigned)v.w << 16));
}

// ---------------- prep: mask + k-quad interleave + bf16 + zero pad ----------------
__global__ __launch_bounds__(256) void prep_interleave(
    const float* __restrict__ Wir, const float* __restrict__ Wiz, const float* __restrict__ Win,
    const float* __restrict__ Whr, const float* __restrict__ Whz, const float* __restrict__ Whn,
    unsigned short* __restrict__ Wv)
{
    const float* srcs[6] = {Wir, Wiz, Win, Whr, Whz, Whn};
    const int kq = blockIdx.x;                    // 0..287
    const int j  = blockIdx.y * 256 + threadIdx.x;
    const int g  = blockIdx.z;
    const float* src = srcs[g];
    ushort4 o;
    unsigned short* po = (unsigned short*)&o;
    #pragma unroll
    for (int u = 0; u < 4; ++u) {
        const int k = 4 * kq + u;
        float w = 0.0f;
        if (k < H_DIM) {
            w = src[(size_t)k * H_DIM + j];
            if (k < j) w = 0.0f;                  // tril mask
        }
        po[u] = f2bf(w);
    }
    ushort4* dst = (ushort4*)Wv + ((size_t)g * NQP + kq) * H_DIM + j;
    *dst = o;
}

__global__ __launch_bounds__(256) void init_h(const float* __restrict__ h0,
                                              float* __restrict__ hbuf,
                                              unsigned* __restrict__ barc)
{
    if (blockIdx.x < 256) {
        const int i = blockIdx.x * 256 + threadIdx.x;
        if (i < B_DIM * H_DIM) hbuf[i] = h0[i];
    } else {
        #pragma unroll
        for (int k = 0; k < 2; ++k) barc[threadIdx.x + 256 * k] = 0u;
    }
}

// x-side partial: acc.x/.y/.z = x @ {Wir,Wiz,Win} slice (zero-inits acc)
__device__ __forceinline__ void x_phase(float4 (&acc)[8], const float4 (*sxh)[17],
    const ushort4* g0, const ushort4* g1, const ushort4* g2,
    int qs, int kq0, int QPH)
{
    #pragma unroll
    for (int i = 0; i < 8; ++i) acc[i] = make_float4(0.f, 0.f, 0.f, 0.f);
    int qi  = qs * H_DIM;
    int row = qs - kq0;
    ushort4 c0 = g0[qi], c1 = g1[qi], c2 = g2[qi];
    for (int iq = 0; iq < QPH; ++iq) {
        const int qn = qi + H_DIM;                // prefetch next (pad-safe)
        const ushort4 n0 = g0[qn], n1 = g1[qn], n2 = g2[qn];
        const float4 f0 = bf4_to_f4(c0), f1 = bf4_to_f4(c1), f2 = bf4_to_f4(c2);
        #pragma unroll
        for (int b = 0; b < 8; ++b) {
            const float4 xv = sxh[row][b];
#define AX(c) \
            acc[b].x = fmaf(xv.c, f0.c, acc[b].x); \
            acc[b].y = fmaf(xv.c, f1.c, acc[b].y); \
            acc[b].z = fmaf(xv.c, f2.c, acc[b].z);
            AX(x) AX(y) AX(z) AX(w)
#undef AX
        }
        c0 = n0; c1 = n1; c2 = n2; qi = qn; ++row;
    }
}

// h-side partial: acc.x += h@Whr, acc.y += h@Whz, acc.w += h@Whn
__device__ __forceinline__ void h_phase(float4 (&acc)[8], const float4 (*sxh)[17],
    const ushort4* g3, const ushort4* g4, const ushort4* g5,
    int qs, int kq0, int QPH)
{
    int qi  = qs * H_DIM;
    int row = qs - kq0;
    ushort4 c3 = g3[qi], c4 = g4[qi], c5 = g5[qi];
    for (int iq = 0; iq < QPH; ++iq) {
        const int qn = qi + H_DIM;
        const ushort4 n3 = g3[qn], n4 = g4[qn], n5 = g5[qn];
        const float4 f3 = bf4_to_f4(c3), f4 = bf4_to_f4(c4), f5 = bf4_to_f4(c5);
        #pragma unroll
        for (int b = 0; b < 8; ++b) {
            const float4 hv = sxh[row][8 + b];
#define AH(c) \
            acc[b].x = fmaf(hv.c, f3.c, acc[b].x); \
            acc[b].y = fmaf(hv.c, f4.c, acc[b].y); \
            acc[b].w = fmaf(hv.c, f5.c, acc[b].w);
            AH(x) AH(y) AH(z) AH(w)
#undef AH
        }
        c3 = n3; c4 = n4; c5 = n5; qi = qn; ++row;
    }
}

// ---------------- main: 256 WGs x 1024 threads, x-side pipelined into sync shadow ----
__global__ __launch_bounds__(1024, 4) void gru_main(
    const float* __restrict__ x,      // [T,B,H]
    const unsigned short* __restrict__ Wv, // [6,NQP,H,4] bf16
    const float* __restrict__ bir, const float* __restrict__ bhr,
    const float* __restrict__ biz, const float* __restrict__ bhz,
    const float* __restrict__ bin_, const float* __restrict__ bhn,
    const float* __restrict__ Wout, const float* __restrict__ bout,
    float* __restrict__ hbuf,         // [2,B,H]
    float* __restrict__ pmax,         // [T,B,32]
    unsigned* __restrict__ barc)      // [8][64]
{
    __shared__ float4 sxh[NQP][17];   // [kq_rel][c] c<8: x rows b0..b0+7, c 8..15: h rows
    __shared__ float4 red[16][8][16]; // [wave][b][jl] sk-folded partials (r,z,ni,nh)
    __shared__ float  mxs[8][2];      // [b][blk] label maxes

    const int tid  = threadIdx.x;
    const int lane = tid & 63;
    const int jl   = lane & 15;
    const int sk   = lane >> 4;
    const int ww   = tid >> 6;        // 0..15
    const int blkw = ww >> 3;
    const int wb   = ww & 7;

    const int pair = blockIdx.x & 31;
    const int bg   = blockIdx.x >> 5; // 0..7 barrier group
    const int b0   = bg * 8;

    const int kq0   = 4 * pair;
    const int nreal = 256 - kq0;

    const int Q0A  = 4 * pair;
    const int QPHA = (256 - 4 * pair + 31) >> 5;   // 5..8
    const int Q0B  = 4 * (63 - pair);
    const int QPHB = (4 * pair + 4 + 31) >> 5;     // 1..4  (QPHA+QPHB == 9)

    const int j0  = blkw ? 16 * (63 - pair) : 16 * pair;
    const int Q0  = blkw ? Q0B : Q0A;
    const int QPH = blkw ? QPHB : QPHA;
    const int slot = (wb << 2) | sk;
    const int qs  = Q0 + slot * QPH;
    const int j   = j0 + jl;

    // epilogue per-thread constants (tid<256: blk = tid>>7, b = (tid>>4)&7, jl = tid&15)
    const int ejl = tid & 15;
    const int eb  = (tid >> 4) & 7;
    const int ej  = ((tid >> 7) ? 16 * (63 - pair) : 16 * pair) + ejl;
    float c_bir = 0, c_bhr = 0, c_biz = 0, c_bhz = 0, c_bin = 0, c_bhn = 0, c_wo = 0, bo = 0;
    if (tid < 256) {
        c_bir = bir[ej]; c_bhr = bhr[ej]; c_biz = biz[ej]; c_bhz = bhz[ej];
        c_bin = bin_[ej]; c_bhn = bhn[ej]; c_wo = Wout[ej]; bo = bout[0];
    }

    const ushort4* Wv4 = (const ushort4*)Wv;
    const ushort4* g0 = Wv4 + (size_t)0 * NQP * H_DIM + j;
    const ushort4* g1 = Wv4 + (size_t)1 * NQP * H_DIM + j;
    const ushort4* g2 = Wv4 + (size_t)2 * NQP * H_DIM + j;
    const ushort4* g3 = Wv4 + (size_t)3 * NQP * H_DIM + j;
    const ushort4* g4 = Wv4 + (size_t)4 * NQP * H_DIM + j;
    const ushort4* g5 = Wv4 + (size_t)5 * NQP * H_DIM + j;

    unsigned* mybar = barc + bg * 64;

    // zero sxh once: pad rows (>= nreal) must stay zero
    for (int i = tid; i < NQP * 17; i += 1024)
        ((float4*)sxh)[i] = make_float4(0.f, 0.f, 0.f, 0.f);
    __syncthreads();

    float4 acc[8];                    // loop-carried: x-side of step t+1 computed at tail of t

    // ---- prologue: stage x(0) (all 16 waves), then x-phase(0) ----
    {
        const int ch = ww & 7, half = ww >> 3;
        const float* src = x + (size_t)(b0 + ch) * H_DIM;
        #pragma unroll
        for (int it = 0; it < 2; ++it) {
            const int r = lane + 64 * (half * 2 + it);
            if (r < nreal) sxh[r][ch] = *(const float4*)(src + 4 * (kq0 + r));
        }
    }
    __syncthreads();
    x_phase(acc, sxh, g0, g1, g2, qs, kq0, QPH);

    for (int t = 0; t < T_DIM; ++t) {
        const float* hid  = hbuf + (size_t)(t & 1) * (B_DIM * H_DIM);
        float*       hidn = hbuf + (size_t)((t + 1) & 1) * (B_DIM * H_DIM);

        // ---- wait: h(t) visible (arrivals of step t-1); t=0 trivially passes ----
        if (tid == 0) {
            const unsigned tgt = 32u * (unsigned)t;
            while (__hip_atomic_load(mybar, __ATOMIC_RELAXED, __HIP_MEMORY_SCOPE_AGENT) < tgt)
                __builtin_amdgcn_s_sleep(1);
        }
        __syncthreads();

        // ---- stage h(t): all 16 waves, 2 loads/thread ----
        {
            const int ch = ww & 7, half = ww >> 3;
            float* src = (float*)hid + (size_t)(b0 + ch) * H_DIM;
            #pragma unroll
            for (int it = 0; it < 2; ++it) {
                const int r = lane + 64 * (half * 2 + it);
                if (r < nreal) {
                    float* s4 = src + 4 * (kq0 + r);
                    float4 v;   // agent-scope loads: read h at the coherence point
                    v.x = __hip_atomic_load(s4 + 0, __ATOMIC_RELAXED, __HIP_MEMORY_SCOPE_AGENT);
                    v.y = __hip_atomic_load(s4 + 1, __ATOMIC_RELAXED, __HIP_MEMORY_SCOPE_AGENT);
                    v.z = __hip_atomic_load(s4 + 2, __ATOMIC_RELAXED, __HIP_MEMORY_SCOPE_AGENT);
                    v.w = __hip_atomic_load(s4 + 3, __ATOMIC_RELAXED, __HIP_MEMORY_SCOPE_AGENT);
                    sxh[r][8 + ch] = v;
                }
            }
        }
        __syncthreads();

        // ---- capture epilogue scalars before x-slots get overwritten later ----
        float exv = 0.f, ehv = 0.f;
        if (tid < 256) {
            const int rr = (ej >> 2) - kq0;
            exv = ((const float*)&sxh[rr][eb])[ej & 3];
            ehv = ((const float*)&sxh[rr][8 + eb])[ej & 3];
        }

        // ---- h-phase: acc += h-side (acc already holds x-side of step t) ----
        h_phase(acc, sxh, g3, g4, g5, qs, kq0, QPH);

        // ---- fold sk sub-slots, write per-wave partials ----
        #pragma unroll
        for (int b = 0; b < 8; ++b) {
            acc[b].x += __shfl_xor(acc[b].x, 16); acc[b].y += __shfl_xor(acc[b].y, 16);
            acc[b].z += __shfl_xor(acc[b].z, 16); acc[b].w += __shfl_xor(acc[b].w, 16);
            acc[b].x += __shfl_xor(acc[b].x, 32); acc[b].y += __shfl_xor(acc[b].y, 32);
            acc[b].z += __shfl_xor(acc[b].z, 32); acc[b].w += __shfl_xor(acc[b].w, 32);
        }
        if (lane < 16) {
            #pragma unroll
            for (int b = 0; b < 8; ++b) red[ww][b][jl] = acc[b];
        }
        __syncthreads();

        // ---- epilogue (waves 0-3)  ||  stage x(t+1) (waves 8-15) ----
        if (tid < 256) {
            const int blk = tid >> 7;
            const int wbase = blk * 8;
            float4 s = red[wbase][eb][ejl];
            #pragma unroll
            for (int w2 = 1; w2 < 8; ++w2) {
                const float4 v = red[wbase + w2][eb][ejl];
                s.x += v.x; s.y += v.y; s.z += v.z; s.w += v.w;
            }
            const float rp = s.x + c_bir * exv + c_bhr;
            const float zp = s.y + c_biz * exv + c_bhz;
            const float r  = 1.0f / (1.0f + expf(-rp));
            const float z  = 1.0f / (1.0f + expf(-zp));
            const float np = s.z + c_bin * exv + r * (s.w + c_bhn);
            const float n  = tanhf(np);
            const float hnew = ehv * z + (1.0f - z) * n;
            __hip_atomic_store(&hidn[(size_t)(b0 + eb) * H_DIM + ej], hnew,
                               __ATOMIC_RELAXED, __HIP_MEMORY_SCOPE_AGENT);
            float lab = (1.0f / (1.0f + expf(-(hnew * c_wo + bo)))) * exv;
            #pragma unroll
            for (int off = 8; off; off >>= 1)
                lab = fmaxf(lab, __shfl_xor(lab, off));
            if (ejl == 0) mxs[eb][blk] = lab;
        } else if (ww >= 8 && t < T_DIM - 1) {
            const int c = ww - 8;
            const float* src = x + ((size_t)(t + 1) * B_DIM + b0 + c) * H_DIM;
            #pragma unroll
            for (int it = 0; it < 4; ++it) {
                const int r = (tid & 63) + (it << 6);
                if (r < nreal) sxh[r][c] = *(const float4*)(src + 4 * (kq0 + r));
            }
        }
        __syncthreads();

        if (tid < 8)
            pmax[((size_t)t * B_DIM + b0 + tid) * 32 + pair] = fmaxf(mxs[tid][0], mxs[tid][1]);

        // ---- arrive EARLY, then hide barrier latency under x-phase(t+1) ----
        if (tid == 0)
            __hip_atomic_fetch_add(mybar, 1u, __ATOMIC_RELEASE, __HIP_MEMORY_SCOPE_AGENT);

        if (t < T_DIM - 1)
            x_phase(acc, sxh, g0, g1, g2, qs, kq0, QPH);
    }
}

// ---------------- finalize ----------------
__global__ __launch_bounds__(256) void finalize(const float* __restrict__ pmax, int* __restrict__ out)
{
    const int i = blockIdx.x * 256 + threadIdx.x; // 0..T*B-1
    if (i >= T_DIM * B_DIM) return;
    const float4* pm = (const float4*)(pmax + (size_t)i * 32);
    float m = -3.4e38f;
    #pragma unroll
    for (int q = 0; q < 8; ++q) {
        const float4 v = pm[q];
        m = fmaxf(m, fmaxf(fmaxf(v.x, v.y), fmaxf(v.z, v.w)));
    }
    out[i] = (m >= 0.5f) ? 1 : -1;
}

extern "C" void kernel_launch(void* const* d_in, const int* in_sizes, int n_in,
                              void* d_out, int out_size, void* d_ws, size_t ws_size,
                              hipStream_t stream)
{
    const float* x    = (const float*)d_in[0];
    const float* h0   = (const float*)d_in[1];
    const float* W_ir = (const float*)d_in[2];
    const float* W_hr = (const float*)d_in[3];
    const float* W_iz = (const float*)d_in[4];
    const float* W_hz = (const float*)d_in[5];
    const float* W_in = (const float*)d_in[6];
    const float* W_hn = (const float*)d_in[7];
    const float* b_ir = (const float*)d_in[8];
    const float* b_hr = (const float*)d_in[9];
    const float* b_iz = (const float*)d_in[10];
    const float* b_hz = (const float*)d_in[11];
    const float* b_in = (const float*)d_in[12];
    const float* b_hn = (const float*)d_in[13];
    const float* W_out = (const float*)d_in[14];
    const float* b_out = (const float*)d_in[15];

    unsigned short* Wv = (unsigned short*)d_ws;              // 6*NQP*H*4 bf16 (~14.2 MB)
    float* hbuf = (float*)(Wv + (size_t)6 * NQP * H_DIM * 4);// 2*B*H f32
    float* pmax = hbuf + (size_t)2 * B_DIM * H_DIM;          // T*B*32 f32 (4 MB)
    unsigned* barc = (unsigned*)(pmax + (size_t)T_DIM * B_DIM * 32); // 8*64 u32

    prep_interleave<<<dim3(NQP, 4, 6), 256, 0, stream>>>(W_ir, W_iz, W_in, W_hr, W_hz, W_hn, Wv);
    init_h<<<dim3(257), 256, 0, stream>>>(h0, hbuf, barc);

    void* args[] = {(void*)&x, (void*)&Wv,
                    (void*)&b_ir, (void*)&b_hr, (void*)&b_iz, (void*)&b_hz,
                    (void*)&b_in, (void*)&b_hn, (void*)&W_out, (void*)&b_out,
                    (void*)&hbuf, (void*)&pmax, (void*)&barc};
    hipError_t rc = hipLaunchCooperativeKernel((const void*)gru_main, dim3(256), dim3(1024), args, 0, stream);
    (void)rc;

    finalize<<<dim3(T_DIM * B_DIM / 256), 256, 0, stream>>>(pmax, (int*)d_out);
}